// Round 4
// baseline (162.421 us; speedup 1.0000x reference)
//
#include <hip/hip_runtime.h>
#include <hip/hip_bf16.h>
#include <stdint.h>

// RNDiscriminator: B=64, d^2=64 positions, 26 features, g: 52->256->256, f: 256->1
// h1[i,j] = relu(u'[j] + v[i]); dominant cost sum_ij relu(h1 @ W2 + b2) = 34.4 GF bf16.
//
// k3: W2 fragments live in REGISTERS (128 VGPR/wave, loaded once, reused over 8
// pairs). h1 tile staged per pair in 32 KB LDS (XOR-swizzled). Hot loop =
// ds_read_b128 + MFMA only. 512 blocks x 256 thr = 2 blocks/CU, 2 waves/SIMD.

typedef float f32x4 __attribute__((ext_vector_type(4)));
typedef short short8 __attribute__((ext_vector_type(8)));

__device__ __forceinline__ uint32_t cvt_pk_bf16(float lo, float hi) {
    uint32_t r;
    asm("v_cvt_pk_bf16_f32 %0, %1, %2" : "=v"(r) : "v"(lo), "v"(hi));
    return r;
}

// K12: fused conv(8x8/s8)+relu+coords -> x tile in LDS -> u,v rows.
// block g: b = g>>2, positions q*16..q*16+15 (q = g&3).
__global__ void k12_conv_uv(const float* __restrict__ img, const float* __restrict__ cw,
                            const float* __restrict__ cb, const float* __restrict__ w1,
                            const float* __restrict__ b1, float* __restrict__ u,
                            float* __restrict__ v) {
    __shared__ float xs[16][26];
    int g = blockIdx.x;
    int b = g >> 2, q = g & 3, p0 = q * 16;
    int t = threadIdx.x;

    // phase 1: 16 positions x 26 channels
    for (int idx = t; idx < 416; idx += 256) {
        int pl = idx / 26;          // 0..15
        int ch = idx - pl * 26;
        int pos = p0 + pl;
        int r = pos >> 3, c = pos & 7;
        float val;
        if (ch < 24) {
            float s = cb[ch];
            #pragma unroll
            for (int ci = 0; ci < 3; ++ci)
                #pragma unroll
                for (int kr = 0; kr < 8; ++kr) {
                    const float* ip = img + ((b * 3 + ci) * 64 + r * 8 + kr) * 64 + c * 8;
                    const float* wp = cw + ((ch * 3 + ci) * 8 + kr) * 8;
                    #pragma unroll
                    for (int kc = 0; kc < 8; ++kc) s += ip[kc] * wp[kc];
                }
            val = fmaxf(s, 0.f);
        } else if (ch == 24) {
            val = -1.f + (2.f / 7.f) * (float)c;
        } else {
            val = -1.f + (2.f / 7.f) * (float)r;
        }
        xs[pl][ch] = val;
    }
    __syncthreads();

    // phase 2: thread c computes u,v col c for the 16 rows
    int c = t;
    for (int r = 0; r < 16; ++r) {
        float su = b1[c], sv = 0.f;
        #pragma unroll
        for (int k = 0; k < 26; ++k) {
            float xv = xs[r][k];
            su += xv * w1[k * 256 + c];
            sv += xv * w1[(26 + k) * 256 + c];
        }
        int bj = b * 64 + p0 + r;
        u[bj * 256 + c] = su;
        v[bj * 256 + c] = sv;
    }
}

// K2b: pre-fragment W2 for MFMA B-operand, fragment-major:
// fi = ks*16 + ni2;  lane l holds B[k = ks*32+(l>>4)*8+e][n = ni2*16+(l&15)]
__global__ void k2b_w2f(const float* __restrict__ w2, short* __restrict__ w2f) {
    int fi = blockIdx.x;       // 0..127
    int l  = threadIdx.x;      // 0..63
    int ks = fi >> 4, ni2 = fi & 15;
    int n  = ni2 * 16 + (l & 15);
    int k0 = ks * 32 + (l >> 4) * 8;
    float f[8];
    #pragma unroll
    for (int e = 0; e < 8; ++e) f[e] = w2[(k0 + e) * 256 + n];
    union { short8 s; uint32_t w[4]; } A;
    A.w[0] = cvt_pk_bf16(f[0], f[1]);
    A.w[1] = cvt_pk_bf16(f[2], f[3]);
    A.w[2] = cvt_pk_bf16(f[4], f[5]);
    A.w[3] = cvt_pk_bf16(f[6], f[7]);
    *(short8*)(w2f + (fi * 64 + l) * 8) = A.s;
}

// K3: block = (b, 8 consecutive i's). Per wave: 64 cols resident as 32 B-frags
// (128 VGPR). Per unit: stage h1 (64x256 bf16 LDS), ds_read+MFMA, relu+bias
// colsum accumulated in regs across units; one flush -> part[blk][256].
__global__ __launch_bounds__(256, 2) void k3_pairs(
        const float* __restrict__ u, const float* __restrict__ v,
        const short* __restrict__ w2f, const float* __restrict__ b2,
        float* __restrict__ part) {
    __shared__ short h1s[64 * 256];   // 32 KB
    int t = threadIdx.x;
    int lane = t & 63, wv = t >> 6;
    int lr = lane & 15, lg = lane >> 4;
    int blk = blockIdx.x;             // 0..511
    int b = blk >> 3, i0 = (blk & 7) * 8;

    // resident B fragments: Bf[ks][cg], cg = nh*2+ni, col-group = wv*4+cg
    short8 Bf[8][4];
    #pragma unroll
    for (int ks = 0; ks < 8; ++ks)
        #pragma unroll
        for (int cg = 0; cg < 4; ++cg)
            Bf[ks][cg] = *(const short8*)(w2f + ((ks * 16 + wv * 4 + cg) * 64 + lane) * 8);

    float bias[4];
    #pragma unroll
    for (int cg = 0; cg < 4; ++cg) bias[cg] = b2[wv * 64 + cg * 16 + lr];

    float csum[4] = {0.f, 0.f, 0.f, 0.f};
    const float* ub = u + b * 64 * 256;
    int kq = lane * 4;

    #pragma unroll 1
    for (int qq = 0; qq < 8; ++qq) {
        const float* vp = v + (b * 64 + i0 + qq) * 256;
        float4 vv = *(const float4*)(vp + kq);
        // ---- stage h1 rows rr*4+wv ----
        #pragma unroll 8
        for (int rr = 0; rr < 16; ++rr) {
            int row = rr * 4 + wv;
            float4 uu = *(const float4*)(ub + row * 256 + kq);
            int2 w;
            w.x = (int)cvt_pk_bf16(fmaxf(uu.x + vv.x, 0.f), fmaxf(uu.y + vv.y, 0.f));
            w.y = (int)cvt_pk_bf16(fmaxf(uu.z + vv.z, 0.f), fmaxf(uu.w + vv.w, 0.f));
            int byte = (row * 512 + kq * 2) ^ ((row & 7) << 4);
            *(int2*)((char*)h1s + byte) = w;
        }
        __syncthreads();

        // ---- compute: 2 n-halves to bound acc regs ----
        __builtin_amdgcn_s_setprio(1);
        #pragma unroll 1
        for (int nh = 0; nh < 2; ++nh) {
            f32x4 acc[4][2];
            #pragma unroll
            for (int mi = 0; mi < 4; ++mi)
                #pragma unroll
                for (int ni = 0; ni < 2; ++ni) acc[mi][ni] = (f32x4){0.f, 0.f, 0.f, 0.f};
            #pragma unroll
            for (int ks = 0; ks < 8; ++ks) {
                short8 a[4];
                #pragma unroll
                for (int mi = 0; mi < 4; ++mi) {
                    int row = mi * 16 + lr;
                    int byte = (row * 512 + (ks * 32 + lg * 8) * 2) ^ ((row & 7) << 4);
                    a[mi] = *(const short8*)((const char*)h1s + byte);
                }
                #pragma unroll
                for (int ni = 0; ni < 2; ++ni)
                    #pragma unroll
                    for (int mi = 0; mi < 4; ++mi)
                        acc[mi][ni] = __builtin_amdgcn_mfma_f32_16x16x32_bf16(
                            a[mi], Bf[ks][nh * 2 + ni], acc[mi][ni], 0, 0, 0);
            }
            // epilogue: relu(C+bias) partial column-sum into csum
            #pragma unroll
            for (int ni = 0; ni < 2; ++ni) {
                int cg = nh * 2 + ni;
                float s = 0.f;
                #pragma unroll
                for (int mi = 0; mi < 4; ++mi)
                    #pragma unroll
                    for (int r = 0; r < 4; ++r)
                        s += fmaxf(acc[mi][ni][r] + bias[cg], 0.f);
                csum[cg] += s;
            }
        }
        __builtin_amdgcn_s_setprio(0);
        __syncthreads();
    }

    // flush: reduce over lg groups; lanes 0-15 store
    #pragma unroll
    for (int cg = 0; cg < 4; ++cg) {
        float s = csum[cg];
        s += __shfl_xor(s, 16);
        s += __shfl_xor(s, 32);
        if (lane < 16) part[blk * 256 + wv * 64 + cg * 16 + lr] = s;
    }
}

// K5: pooled[b] = sum of 8 part rows; then f-head.
__global__ void k5_head(const float* __restrict__ part, const float* __restrict__ fw1,
                        const float* __restrict__ fb1, const float* __restrict__ fw2,
                        const float* __restrict__ fb2, float* __restrict__ out) {
    __shared__ float P[256];
    __shared__ float wsum[4];
    int b = blockIdx.x, t = threadIdx.x;
    float s0 = 0.f;
    #pragma unroll
    for (int g = 0; g < 8; ++g) s0 += part[(b * 8 + g) * 256 + t];
    P[t] = s0;
    __syncthreads();
    float s = fb1[t];
    for (int k = 0; k < 256; ++k) s += P[k] * fw1[k * 256 + t];
    float h = fmaxf(s, 0.f);
    float p = h * fw2[t];
    #pragma unroll
    for (int off = 32; off >= 1; off >>= 1) p += __shfl_xor(p, off);
    if ((t & 63) == 0) wsum[t >> 6] = p;
    __syncthreads();
    if (t == 0) out[b] = wsum[0] + wsum[1] + wsum[2] + wsum[3] + fb2[0];
}

extern "C" void kernel_launch(void* const* d_in, const int* in_sizes, int n_in,
                              void* d_out, int out_size, void* d_ws, size_t ws_size,
                              hipStream_t stream) {
    const float* image  = (const float*)d_in[0];
    const float* conv_w = (const float*)d_in[1];
    const float* conv_b = (const float*)d_in[2];
    const float* g_w1   = (const float*)d_in[3];
    const float* g_b1   = (const float*)d_in[4];
    const float* g_w2   = (const float*)d_in[5];
    const float* g_b2   = (const float*)d_in[6];
    const float* f_w1   = (const float*)d_in[7];
    const float* f_b1   = (const float*)d_in[8];
    const float* f_w2   = (const float*)d_in[9];
    const float* f_b2   = (const float*)d_in[10];
    float* out = (float*)d_out;

    char* ws = (char*)d_ws;
    float* u    = (float*)(ws + 0);          // 64*64*256*4 = 4 MB
    float* v    = (float*)(ws + 4194304);    // 4 MB
    short* w2f  = (short*)(ws + 8388608);    // 128 KB
    float* part = (float*)(ws + 8519680);    // 512*256*4 = 512 KB

    k12_conv_uv<<<256, 256, 0, stream>>>(image, conv_w, conv_b, g_w1, g_b1, u, v);
    k2b_w2f<<<128, 64, 0, stream>>>(g_w2, w2f);
    k3_pairs<<<512, 256, 0, stream>>>(u, v, w2f, g_b2, part);
    k5_head<<<64, 256, 0, stream>>>(part, f_w1, f_b1, f_w2, f_b2, out);
}

// Round 5
// 76.663 us; speedup vs baseline: 2.1186x; 2.1186x over previous
//
#include <hip/hip_runtime.h>
#include <hip/hip_bf16.h>
#include <stdint.h>

// RNDiscriminator: B=64, d^2=64 positions, 26 features, g: 52->256->256, f: 256->1
// h1[i,j] = relu(u'[j] + v[i]); dominant cost sum_ij relu(h1 @ W2 + b2) = 34.4 GF bf16.
//
// k3: W2 fragments resident in REGISTERS (Bf[8][4], 128 VGPR, ALL indices
// compile-time -- rule #20: any runtime index sends the array to scratch, which
// was R3's 404MB FETCH regression). h1 staged per pair in 32 KB LDS
// (XOR-swizzled). Hot loop = ds_read_b128 + MFMA only; no global loads.

typedef float f32x4 __attribute__((ext_vector_type(4)));
typedef short short8 __attribute__((ext_vector_type(8)));

__device__ __forceinline__ uint32_t cvt_pk_bf16(float lo, float hi) {
    uint32_t r;
    asm("v_cvt_pk_bf16_f32 %0, %1, %2" : "=v"(r) : "v"(lo), "v"(hi));
    return r;
}

// K12: fused conv(8x8/s8)+relu+coords -> x tile in LDS -> u,v rows.
__global__ void k12_conv_uv(const float* __restrict__ img, const float* __restrict__ cw,
                            const float* __restrict__ cb, const float* __restrict__ w1,
                            const float* __restrict__ b1, float* __restrict__ u,
                            float* __restrict__ v) {
    __shared__ float xs[16][26];
    int g = blockIdx.x;
    int b = g >> 2, q = g & 3, p0 = q * 16;
    int t = threadIdx.x;

    for (int idx = t; idx < 416; idx += 256) {
        int pl = idx / 26;
        int ch = idx - pl * 26;
        int pos = p0 + pl;
        int r = pos >> 3, c = pos & 7;
        float val;
        if (ch < 24) {
            float s = cb[ch];
            #pragma unroll
            for (int ci = 0; ci < 3; ++ci)
                #pragma unroll
                for (int kr = 0; kr < 8; ++kr) {
                    const float* ip = img + ((b * 3 + ci) * 64 + r * 8 + kr) * 64 + c * 8;
                    const float* wp = cw + ((ch * 3 + ci) * 8 + kr) * 8;
                    #pragma unroll
                    for (int kc = 0; kc < 8; ++kc) s += ip[kc] * wp[kc];
                }
            val = fmaxf(s, 0.f);
        } else if (ch == 24) {
            val = -1.f + (2.f / 7.f) * (float)c;
        } else {
            val = -1.f + (2.f / 7.f) * (float)r;
        }
        xs[pl][ch] = val;
    }
    __syncthreads();

    int c = t;
    for (int r = 0; r < 16; ++r) {
        float su = b1[c], sv = 0.f;
        #pragma unroll
        for (int k = 0; k < 26; ++k) {
            float xv = xs[r][k];
            su += xv * w1[k * 256 + c];
            sv += xv * w1[(26 + k) * 256 + c];
        }
        int bj = b * 64 + p0 + r;
        u[bj * 256 + c] = su;
        v[bj * 256 + c] = sv;
    }
}

// K2b: pre-fragment W2 for MFMA B-operand, fragment-major:
// fi = ks*16 + ni2;  lane l holds B[k = ks*32+(l>>4)*8+e][n = ni2*16+(l&15)]
__global__ void k2b_w2f(const float* __restrict__ w2, short* __restrict__ w2f) {
    int fi = blockIdx.x;       // 0..127
    int l  = threadIdx.x;      // 0..63
    int ks = fi >> 4, ni2 = fi & 15;
    int n  = ni2 * 16 + (l & 15);
    int k0 = ks * 32 + (l >> 4) * 8;
    float f[8];
    #pragma unroll
    for (int e = 0; e < 8; ++e) f[e] = w2[(k0 + e) * 256 + n];
    union { short8 s; uint32_t w[4]; } A;
    A.w[0] = cvt_pk_bf16(f[0], f[1]);
    A.w[1] = cvt_pk_bf16(f[2], f[3]);
    A.w[2] = cvt_pk_bf16(f[4], f[5]);
    A.w[3] = cvt_pk_bf16(f[6], f[7]);
    *(short8*)(w2f + (fi * 64 + l) * 8) = A.s;
}

// K3: block = (b, 8 consecutive i's). Per wave: 64 cols resident as Bf[8][4]
// (128 VGPR, static indexing ONLY). Per unit: stage h1 (64x256 bf16 LDS,
// XOR-swizzled), 32x ds_read_b128 + 128x MFMA, relu+bias colsum in regs.
__global__ __launch_bounds__(256, 2) void k3_pairs(
        const float* __restrict__ u, const float* __restrict__ v,
        const short* __restrict__ w2f, const float* __restrict__ b2,
        float* __restrict__ part) {
    __shared__ short h1s[64 * 256];   // 32 KB
    int t = threadIdx.x;
    int lane = t & 63, wv = t >> 6;
    int lr = lane & 15, lg = lane >> 4;
    int blk = blockIdx.x;             // 0..511
    int b = blk >> 3, i0 = (blk & 7) * 8;

    // resident B fragments (all accesses below use literal indices)
    short8 Bf[8][4];
    #pragma unroll
    for (int ks = 0; ks < 8; ++ks)
        #pragma unroll
        for (int cg = 0; cg < 4; ++cg)
            Bf[ks][cg] = *(const short8*)(w2f + ((ks * 16 + wv * 4 + cg) * 64 + lane) * 8);

    float bias[4];
    #pragma unroll
    for (int cg = 0; cg < 4; ++cg) bias[cg] = b2[wv * 64 + cg * 16 + lr];

    float csum[4] = {0.f, 0.f, 0.f, 0.f};
    const float* ub = u + b * 64 * 256;
    int kq = lane * 4;

    #pragma unroll 1
    for (int qq = 0; qq < 8; ++qq) {
        const float* vp = v + (b * 64 + i0 + qq) * 256;
        float4 vv = *(const float4*)(vp + kq);
        // ---- stage h1 rows rr*4+wv (XOR-swizzled bf16) ----
        #pragma unroll 8
        for (int rr = 0; rr < 16; ++rr) {
            int row = rr * 4 + wv;
            float4 uu = *(const float4*)(ub + row * 256 + kq);
            int2 w;
            w.x = (int)cvt_pk_bf16(fmaxf(uu.x + vv.x, 0.f), fmaxf(uu.y + vv.y, 0.f));
            w.y = (int)cvt_pk_bf16(fmaxf(uu.z + vv.z, 0.f), fmaxf(uu.w + vv.w, 0.f));
            int byte = (row * 512 + kq * 2) ^ ((row & 7) << 4);
            *(int2*)((char*)h1s + byte) = w;
        }
        __syncthreads();

        // ---- compute: fully static acc[4][4] ----
        __builtin_amdgcn_s_setprio(1);
        f32x4 acc[4][4];
        #pragma unroll
        for (int mi = 0; mi < 4; ++mi)
            #pragma unroll
            for (int cg = 0; cg < 4; ++cg) acc[mi][cg] = (f32x4){0.f, 0.f, 0.f, 0.f};

        #pragma unroll
        for (int ks = 0; ks < 8; ++ks) {
            short8 a[4];
            #pragma unroll
            for (int mi = 0; mi < 4; ++mi) {
                int row = mi * 16 + lr;
                int byte = (row * 512 + (ks * 32 + lg * 8) * 2) ^ ((row & 7) << 4);
                a[mi] = *(const short8*)((const char*)h1s + byte);
            }
            #pragma unroll
            for (int cg = 0; cg < 4; ++cg)
                #pragma unroll
                for (int mi = 0; mi < 4; ++mi)
                    acc[mi][cg] = __builtin_amdgcn_mfma_f32_16x16x32_bf16(
                        a[mi], Bf[ks][cg], acc[mi][cg], 0, 0, 0);
        }
        __builtin_amdgcn_s_setprio(0);

        // epilogue: relu(C+bias) partial column-sum into csum
        #pragma unroll
        for (int cg = 0; cg < 4; ++cg) {
            float s = 0.f;
            #pragma unroll
            for (int mi = 0; mi < 4; ++mi)
                #pragma unroll
                for (int r = 0; r < 4; ++r)
                    s += fmaxf(acc[mi][cg][r] + bias[cg], 0.f);
            csum[cg] += s;
        }
        __syncthreads();
    }

    // flush: reduce over lg groups; lanes 0-15 store
    #pragma unroll
    for (int cg = 0; cg < 4; ++cg) {
        float s = csum[cg];
        s += __shfl_xor(s, 16);
        s += __shfl_xor(s, 32);
        if (lane < 16) part[blk * 256 + wv * 64 + cg * 16 + lr] = s;
    }
}

// K5: pooled[b] = sum of 8 part rows; then f-head.
__global__ void k5_head(const float* __restrict__ part, const float* __restrict__ fw1,
                        const float* __restrict__ fb1, const float* __restrict__ fw2,
                        const float* __restrict__ fb2, float* __restrict__ out) {
    __shared__ float P[256];
    __shared__ float wsum[4];
    int b = blockIdx.x, t = threadIdx.x;
    float s0 = 0.f;
    #pragma unroll
    for (int g = 0; g < 8; ++g) s0 += part[(b * 8 + g) * 256 + t];
    P[t] = s0;
    __syncthreads();
    float s = fb1[t];
    for (int k = 0; k < 256; ++k) s += P[k] * fw1[k * 256 + t];
    float h = fmaxf(s, 0.f);
    float p = h * fw2[t];
    #pragma unroll
    for (int off = 32; off >= 1; off >>= 1) p += __shfl_xor(p, off);
    if ((t & 63) == 0) wsum[t >> 6] = p;
    __syncthreads();
    if (t == 0) out[b] = wsum[0] + wsum[1] + wsum[2] + wsum[3] + fb2[0];
}

extern "C" void kernel_launch(void* const* d_in, const int* in_sizes, int n_in,
                              void* d_out, int out_size, void* d_ws, size_t ws_size,
                              hipStream_t stream) {
    const float* image  = (const float*)d_in[0];
    const float* conv_w = (const float*)d_in[1];
    const float* conv_b = (const float*)d_in[2];
    const float* g_w1   = (const float*)d_in[3];
    const float* g_b1   = (const float*)d_in[4];
    const float* g_w2   = (const float*)d_in[5];
    const float* g_b2   = (const float*)d_in[6];
    const float* f_w1   = (const float*)d_in[7];
    const float* f_b1   = (const float*)d_in[8];
    const float* f_w2   = (const float*)d_in[9];
    const float* f_b2   = (const float*)d_in[10];
    float* out = (float*)d_out;

    char* ws = (char*)d_ws;
    float* u    = (float*)(ws + 0);          // 64*64*256*4 = 4 MB
    float* v    = (float*)(ws + 4194304);    // 4 MB
    short* w2f  = (short*)(ws + 8388608);    // 128 KB
    float* part = (float*)(ws + 8519680);    // 512*256*4 = 512 KB

    k12_conv_uv<<<256, 256, 0, stream>>>(image, conv_w, conv_b, g_w1, g_b1, u, v);
    k2b_w2f<<<128, 64, 0, stream>>>(g_w2, w2f);
    k3_pairs<<<512, 256, 0, stream>>>(u, v, w2f, g_b2, part);
    k5_head<<<64, 256, 0, stream>>>(part, f_w1, f_b1, f_w2, f_b2, out);
}

// Round 6
// 67.955 us; speedup vs baseline: 2.3901x; 1.1282x over previous
//
#include <hip/hip_runtime.h>
#include <hip/hip_bf16.h>
#include <stdint.h>

// RNDiscriminator: B=64, d^2=64 positions, 26 features, g: 52->256->256, f: 256->1
// h1[i,j] = relu(u'[j] + v[i]); dominant cost sum_ij relu(h1 @ W2 + b2) = 34.4 GF bf16.
//
// k3: Bf[8][4] W2 fragments resident in regs (static indices only -- rule #20).
// h1 DOUBLE-BUFFERED in LDS (2x32KB): STAGE(q+1) || MFMA(q), one barrier/unit.
// b = blk&63 -> all 8 blocks sharing a u-tile land on the same XCD (L2 reuse).

typedef float f32x4 __attribute__((ext_vector_type(4)));
typedef short short8 __attribute__((ext_vector_type(8)));

__device__ __forceinline__ uint32_t cvt_pk_bf16(float lo, float hi) {
    uint32_t r;
    asm("v_cvt_pk_bf16_f32 %0, %1, %2" : "=v"(r) : "v"(lo), "v"(hi));
    return r;
}

// K12: blocks 0..255: fused conv(8x8/s8)+relu+coords -> u,v rows.
//      blocks 256..287: pre-fragment W2 (bf16, fragment-major).
__global__ void k12_front(const float* __restrict__ img, const float* __restrict__ cw,
                          const float* __restrict__ cb, const float* __restrict__ w1,
                          const float* __restrict__ b1, const float* __restrict__ w2,
                          float* __restrict__ u, float* __restrict__ v,
                          short* __restrict__ w2f) {
    int g = blockIdx.x;
    int t = threadIdx.x;
    if (g >= 256) {
        // W2 fragments: fi = ks*16+ni2; lane l holds B[k=ks*32+(l>>4)*8+e][n=ni2*16+(l&15)]
        int fi = (g - 256) * 4 + (t >> 6);
        int l = t & 63;
        int ks = fi >> 4, ni2 = fi & 15;
        int n  = ni2 * 16 + (l & 15);
        int k0 = ks * 32 + (l >> 4) * 8;
        float f[8];
        #pragma unroll
        for (int e = 0; e < 8; ++e) f[e] = w2[(k0 + e) * 256 + n];
        union { short8 s; uint32_t w[4]; } A;
        A.w[0] = cvt_pk_bf16(f[0], f[1]);
        A.w[1] = cvt_pk_bf16(f[2], f[3]);
        A.w[2] = cvt_pk_bf16(f[4], f[5]);
        A.w[3] = cvt_pk_bf16(f[6], f[7]);
        *(short8*)(w2f + (fi * 64 + l) * 8) = A.s;
        return;
    }
    __shared__ float xs[16][26];
    int b = g >> 2, q = g & 3, p0 = q * 16;

    for (int idx = t; idx < 416; idx += 256) {
        int pl = idx / 26;
        int ch = idx - pl * 26;
        int pos = p0 + pl;
        int r = pos >> 3, c = pos & 7;
        float val;
        if (ch < 24) {
            float s = cb[ch];
            #pragma unroll
            for (int ci = 0; ci < 3; ++ci)
                #pragma unroll
                for (int kr = 0; kr < 8; ++kr) {
                    const float* ip = img + ((b * 3 + ci) * 64 + r * 8 + kr) * 64 + c * 8;
                    const float* wp = cw + ((ch * 3 + ci) * 8 + kr) * 8;
                    #pragma unroll
                    for (int kc = 0; kc < 8; ++kc) s += ip[kc] * wp[kc];
                }
            val = fmaxf(s, 0.f);
        } else if (ch == 24) {
            val = -1.f + (2.f / 7.f) * (float)c;
        } else {
            val = -1.f + (2.f / 7.f) * (float)r;
        }
        xs[pl][ch] = val;
    }
    __syncthreads();

    int c = t;
    for (int r = 0; r < 16; ++r) {
        float su = b1[c], sv = 0.f;
        #pragma unroll
        for (int k = 0; k < 26; ++k) {
            float xv = xs[r][k];
            su += xv * w1[k * 256 + c];
            sv += xv * w1[(26 + k) * 256 + c];
        }
        int bj = b * 64 + p0 + r;
        u[bj * 256 + c] = su;
        v[bj * 256 + c] = sv;
    }
}

// K3: block = (b = blk&63, i0 = (blk>>6)*8). Bf resident in regs; h1 double-
// buffered; per unit: STAGE(q+1) -> setprio MFMA(q) -> epilogue -> barrier.
__global__ __launch_bounds__(256, 2) void k3_pairs(
        const float* __restrict__ u, const float* __restrict__ v,
        const short* __restrict__ w2f, const float* __restrict__ b2,
        float* __restrict__ part) {
    __shared__ short h1s[2][64 * 256];   // 64 KB
    __shared__ float vs[8][256];         // 8 KB
    int t = threadIdx.x;
    int lane = t & 63, wv = t >> 6;
    int lr = lane & 15, lg = lane >> 4;
    int blk = blockIdx.x;                 // 0..511
    int b = blk & 63, i0 = (blk >> 6) * 8;

    // stage the 8 v-rows once (2048 floats, 8 per thread)
    {
        int q = t >> 5, c8 = (t & 31) * 8;
        const float* vr = v + (b * 64 + i0 + q) * 256 + c8;
        float4 a0 = *(const float4*)vr;
        float4 a1 = *(const float4*)(vr + 4);
        *(float4*)&vs[q][c8]     = a0;
        *(float4*)&vs[q][c8 + 4] = a1;
    }

    // resident B fragments (static indices only)
    short8 Bf[8][4];
    #pragma unroll
    for (int ks = 0; ks < 8; ++ks)
        #pragma unroll
        for (int cg = 0; cg < 4; ++cg)
            Bf[ks][cg] = *(const short8*)(w2f + ((ks * 16 + wv * 4 + cg) * 64 + lane) * 8);

    float bias[4];
    #pragma unroll
    for (int cg = 0; cg < 4; ++cg) bias[cg] = b2[wv * 64 + cg * 16 + lr];

    const float* ub = u + b * 64 * 256;
    int kq = lane * 4;

    // STAGE(q, buf): h1 rows rr*4+wv = relu(u + vs[q]) -> bf16, XOR-swizzled
    #define STAGE(Q, BUF)                                                          \
    {                                                                              \
        float4 vv = *(const float4*)&vs[Q][kq];                                    \
        _Pragma("unroll 4")                                                        \
        for (int rr = 0; rr < 16; ++rr) {                                          \
            int row = rr * 4 + wv;                                                 \
            float4 uu = *(const float4*)(ub + row * 256 + kq);                     \
            int2 w;                                                                \
            w.x = (int)cvt_pk_bf16(fmaxf(uu.x + vv.x, 0.f),                        \
                                   fmaxf(uu.y + vv.y, 0.f));                       \
            w.y = (int)cvt_pk_bf16(fmaxf(uu.z + vv.z, 0.f),                        \
                                   fmaxf(uu.w + vv.w, 0.f));                       \
            int byte = (row * 512 + kq * 2) ^ ((row & 7) << 4);                    \
            *(int2*)((char*)(BUF) + byte) = w;                                     \
        }                                                                          \
    }

    __syncthreads();            // vs ready
    STAGE(0, h1s[0])
    __syncthreads();            // buf0 ready

    float csum[4] = {0.f, 0.f, 0.f, 0.f};

    #pragma unroll 1
    for (int qq = 0; qq < 8; ++qq) {
        if (qq < 7) STAGE(qq + 1, h1s[(qq + 1) & 1])

        const char* hb = (const char*)h1s[qq & 1];
        __builtin_amdgcn_s_setprio(1);
        f32x4 acc[4][4];
        #pragma unroll
        for (int mi = 0; mi < 4; ++mi)
            #pragma unroll
            for (int cg = 0; cg < 4; ++cg) acc[mi][cg] = (f32x4){0.f, 0.f, 0.f, 0.f};

        #pragma unroll
        for (int ks = 0; ks < 8; ++ks) {
            short8 a[4];
            #pragma unroll
            for (int mi = 0; mi < 4; ++mi) {
                int row = mi * 16 + lr;
                int byte = (row * 512 + (ks * 32 + lg * 8) * 2) ^ ((row & 7) << 4);
                a[mi] = *(const short8*)(hb + byte);
            }
            #pragma unroll
            for (int cg = 0; cg < 4; ++cg)
                #pragma unroll
                for (int mi = 0; mi < 4; ++mi)
                    acc[mi][cg] = __builtin_amdgcn_mfma_f32_16x16x32_bf16(
                        a[mi], Bf[ks][cg], acc[mi][cg], 0, 0, 0);
        }
        __builtin_amdgcn_s_setprio(0);

        // epilogue: relu(C+bias) partial column-sum
        #pragma unroll
        for (int cg = 0; cg < 4; ++cg) {
            float s = 0.f;
            #pragma unroll
            for (int mi = 0; mi < 4; ++mi)
                #pragma unroll
                for (int r = 0; r < 4; ++r)
                    s += fmaxf(acc[mi][cg][r] + bias[cg], 0.f);
            csum[cg] += s;
        }
        __syncthreads();
    }
    #undef STAGE

    // flush: reduce over lg groups; lanes 0-15 store
    #pragma unroll
    for (int cg = 0; cg < 4; ++cg) {
        float s = csum[cg];
        s += __shfl_xor(s, 16);
        s += __shfl_xor(s, 32);
        if (lane < 16) part[blk * 256 + wv * 64 + cg * 16 + lr] = s;
    }
}

// K5: pooled[b] = sum of the 8 part rows for b (blk = b + 64*g); then f-head.
__global__ void k5_head(const float* __restrict__ part, const float* __restrict__ fw1,
                        const float* __restrict__ fb1, const float* __restrict__ fw2,
                        const float* __restrict__ fb2, float* __restrict__ out) {
    __shared__ float P[256];
    __shared__ float wsum[4];
    int b = blockIdx.x, t = threadIdx.x;
    float s0 = 0.f;
    #pragma unroll
    for (int g = 0; g < 8; ++g) s0 += part[(b + 64 * g) * 256 + t];
    P[t] = s0;
    __syncthreads();
    float s = fb1[t];
    for (int k = 0; k < 256; ++k) s += P[k] * fw1[k * 256 + t];
    float h = fmaxf(s, 0.f);
    float p = h * fw2[t];
    #pragma unroll
    for (int off = 32; off >= 1; off >>= 1) p += __shfl_xor(p, off);
    if ((t & 63) == 0) wsum[t >> 6] = p;
    __syncthreads();
    if (t == 0) out[b] = wsum[0] + wsum[1] + wsum[2] + wsum[3] + fb2[0];
}

extern "C" void kernel_launch(void* const* d_in, const int* in_sizes, int n_in,
                              void* d_out, int out_size, void* d_ws, size_t ws_size,
                              hipStream_t stream) {
    const float* image  = (const float*)d_in[0];
    const float* conv_w = (const float*)d_in[1];
    const float* conv_b = (const float*)d_in[2];
    const float* g_w1   = (const float*)d_in[3];
    const float* g_b1   = (const float*)d_in[4];
    const float* g_w2   = (const float*)d_in[5];
    const float* g_b2   = (const float*)d_in[6];
    const float* f_w1   = (const float*)d_in[7];
    const float* f_b1   = (const float*)d_in[8];
    const float* f_w2   = (const float*)d_in[9];
    const float* f_b2   = (const float*)d_in[10];
    float* out = (float*)d_out;

    char* ws = (char*)d_ws;
    float* u    = (float*)(ws + 0);          // 64*64*256*4 = 4 MB
    float* v    = (float*)(ws + 4194304);    // 4 MB
    short* w2f  = (short*)(ws + 8388608);    // 128 KB
    float* part = (float*)(ws + 8519680);    // 512*256*4 = 512 KB

    k12_front<<<288, 256, 0, stream>>>(image, conv_w, conv_b, g_w1, g_b1, g_w2,
                                       u, v, w2f);
    k3_pairs<<<512, 256, 0, stream>>>(u, v, w2f, g_b2, part);
    k5_head<<<64, 256, 0, stream>>>(part, f_w1, f_b1, f_w2, f_b2, out);
}